// Round 3
// baseline (1401.049 us; speedup 1.0000x reference)
//
#include <hip/hip_runtime.h>
#include <stdint.h>

typedef unsigned short u16;
typedef unsigned int u32;
typedef __bf16 bf16x8 __attribute__((ext_vector_type(8)));
typedef float floatx4 __attribute__((ext_vector_type(4)));

#define NEG_INF_F (-10000000.0f)
#define MFMA16 __builtin_amdgcn_mfma_f32_16x16x32_bf16

__device__ __forceinline__ float bf2f(u16 u) {
    union { u32 u; float f; } x; x.u = ((u32)u) << 16; return x.f;
}
__device__ __forceinline__ u16 f2bf(float f) {
    union { float f; u32 u; } x; x.f = f;
    u32 r = x.u + 0x7fffu + ((x.u >> 16) & 1u);   // RNE
    return (u16)(r >> 16);
}

__device__ __forceinline__ void async_cp16(const void* g, void* l) {
    __builtin_amdgcn_global_load_lds(
        (const __attribute__((address_space(1))) void*)g,
        (__attribute__((address_space(3))) void*)l, 16, 0, 0);
}

// ---------------------------------------------------------------------------
// BT GEMM: C[m,n] = sum_k A[m,k] * B[n,k]
// 128x128 tile, 256 threads (4 waves 2x2), mfma_f32_16x16x32_bf16, BK=64,
// global_load_lds width-16 staging + 16B-group XOR swizzle (conflict-free).
// EPI_QKV is a merged dispatch (1536 blocks, uniform work, 6 full CU rounds):
//   blocks    0..1023: QK  = xb @ [Wq|Wk] + bias  -> QKV bf16 [M][2H]
//   blocks 1024..1535: Vt  = WvT @ xb^T + bv      -> Vt  bf16 [b][h][s]
//     (Vt[h][s] = sum_k WvT[h,k] * xb[s,k]; computing V transposed directly
//      deletes the V write + V read + LDS transpose of the old path.)
// EPI_CTX decodes q-tiles heavy-first (byE = 7 - t>>3): LPT pairing makes
//   each CU's 2 sequential blocks sum to equal work (Keff 8+1, 7+2, ...).
// ---------------------------------------------------------------------------
enum { EPI_QKV = 0, EPI_LOGITS = 1, EPI_CTX = 2, EPI_MLP = 3, EPI_OUT = 4 };

template <int EPI>
__global__ __launch_bounds__(256) void gemm_bt(
    const u16* __restrict__ A, int lda, long long aBatch,
    const u16* __restrict__ B, int ldb, long long bBatch,
    void* __restrict__ Cv, int ldc, long long cBatch,
    int K,
    const float* __restrict__ bias,
    const u16* __restrict__ ctxb,      // EPI_MLP: ctx bf16 (read)
    u16* __restrict__ xb,              // EPI_MLP: residual (rw); EPI_QKV: Vt
    float scale, int nx, int ny)
{
    __shared__ __align__(16) u16 sA[128 * 64];   // 16 KB
    __shared__ __align__(16) u16 sB[128 * 64];   // 16 KB

    const int tid  = threadIdx.x;
    const int wave = tid >> 6;
    const int lane = tid & 63;

    int bxE, byE, bz;
    int vt = 0;
    if constexpr (EPI == EPI_LOGITS) {
        bz = blockIdx.x & 7;
        int t = blockIdx.x >> 3;                       // 0..35 triangular
        int tq = (int)((sqrtf(8.0f * t + 1.0f) - 1.0f) * 0.5f);
        while ((tq + 1) * (tq + 2) / 2 <= t) ++tq;
        while (tq * (tq + 1) / 2 > t) --tq;
        bxE = tq;                       // n-tile = query
        byE = t - tq * (tq + 1) / 2;    // m-tile = key (<= tq)
    } else if constexpr (EPI == EPI_CTX) {
        bz = blockIdx.x & 7;
        int t = blockIdx.x >> 3;        // 0..63
        bxE = t & 7;                    // h-tile
        byE = 7 - (t >> 3);             // q-tile, heavy-first (LPT balance)
    } else if constexpr (EPI == EPI_QKV) {
        bz = 0;
        const int k8 = blockIdx.x & 7, rr = blockIdx.x >> 3;
        if (rr < 128) {                 // QK zone: nx=16 decode
            bxE = 2 * k8 + (rr & 1); byE = rr >> 1;
        } else {                        // VT zone: XCD k owns batch k's s-tiles
            vt = 1;
            const int r2 = rr - 128;    // 0..63
            bxE = 8 * k8 + (r2 & 7);    // s-tile (global n)
            byE = r2 >> 3;              // h-tile (m)
        }
    } else {
        bz = 0;
        const int k = blockIdx.x & 7, r = blockIdx.x >> 3;
        if (nx >= 8) { const int xp = nx >> 3; bxE = xp * k + (r % xp); byE = r / xp; }
        else         { bxE = k >> 1; byE = (k & 1) * (ny >> 1) + r; }
    }
    int Keff = K;
    if constexpr (EPI == EPI_CTX) Keff = min(K, (byE + 1) * 128);

    const u16* Ab;
    const u16* Bb;
    if constexpr (EPI == EPI_QKV) {
        if (vt) {  // A = WvT section (rows 2048.. of WqkvT), B = xb
            Ab = B + 2 * 1024 * 1024 + (long long)(byE * 128) * ldb;
            Bb = A + (long long)(bxE * 128) * lda;
        } else {
            Ab = A + (long long)(byE * 128) * lda;
            Bb = B + (long long)(bxE * 128) * ldb;
        }
    } else {
        Ab = A + (long long)bz * aBatch + (long long)(byE * 128) * lda;
        Bb = B + (long long)bz * bBatch + (long long)(bxE * 128) * ldb;
    }

    const int wm = wave >> 1, wn = wave & 1;
    const int quad = lane >> 4;

    const int srowoff = lane >> 3;
    const int gf      = (lane & 7) ^ ((lane >> 3) & 7);

    const int ra = 64 * wm + (lane & 15);
    const int rb = 64 * wn + (lane & 15);
    const int rx7 = lane & 7;

    floatx4 zero = {0.f, 0.f, 0.f, 0.f};
    floatx4 acc[4][4];
#pragma unroll
    for (int i = 0; i < 4; ++i)
#pragma unroll
        for (int j = 0; j < 4; ++j) acc[i][j] = zero;

    for (int k0 = 0; k0 < Keff; k0 += 64) {
#pragma unroll
        for (int i = 0; i < 4; ++i) {
            const int c = wave * 4 + i;
            const int r = c * 8 + srowoff;
            async_cp16(Ab + (long long)r * lda + k0 + gf * 8, &sA[c * 512 + lane * 8]);
            async_cp16(Bb + (long long)r * ldb + k0 + gf * 8, &sB[c * 512 + lane * 8]);
        }
        __syncthreads();

#pragma unroll
        for (int kk = 0; kk < 64; kk += 32) {
            const int gbase = kk >> 3;
            const int ga = ((gbase + quad) ^ rx7) << 3;
            bf16x8 af[4], bf[4];
#pragma unroll
            for (int mi = 0; mi < 4; ++mi)
                af[mi] = *(const bf16x8*)&sA[(ra + 16 * mi) * 64 + ga];
#pragma unroll
            for (int ni = 0; ni < 4; ++ni)
                bf[ni] = *(const bf16x8*)&sB[(rb + 16 * ni) * 64 + ga];
#pragma unroll
            for (int mi = 0; mi < 4; ++mi)
#pragma unroll
                for (int ni = 0; ni < 4; ++ni)
                    acc[mi][ni] = MFMA16(af[mi], bf[ni], acc[mi][ni], 0, 0, 0);
        }
        __syncthreads();
    }

    // epilogue: C/D layout col = lane&15, row = (lane>>4)*4 + reg  [m89]
    const int m0 = byE * 128 + 64 * wm + (quad << 2);
    const int n0 = bxE * 128 + 64 * wn + (lane & 15);
#pragma unroll
    for (int mi = 0; mi < 4; ++mi) {
#pragma unroll
        for (int ni = 0; ni < 4; ++ni) {
            const int gn = n0 + ni * 16;
#pragma unroll
            for (int r = 0; r < 4; ++r) {
                const int gm = m0 + mi * 16 + r;
                float v = acc[mi][ni][r];
                if constexpr (EPI == EPI_QKV) {
                    if (!vt) {
                        v += bias[gn];
                        ((u16*)Cv)[(long long)gm * ldc + gn] = f2bf(v);
                    } else {
                        // Vt[b][h][s]: b = gn>>10, h = gm, s = gn&1023
                        v += bias[2048 + gm];  // bv packed at offset 2H in bqkv
                        xb[((long long)(gn >> 10) << 20) + ((long long)gm << 10)
                           + (gn & 1023)] = f2bf(v);
                    }
                } else if constexpr (EPI == EPI_LOGITS) {
                    v = v * scale + (gm > gn ? NEG_INF_F : 0.0f);  // m=key, n=query
                    ((float*)Cv)[(long long)bz * cBatch + (long long)gm * ldc + gn] = v;
                } else if constexpr (EPI == EPI_CTX) {
                    ((u16*)Cv)[(long long)bz * cBatch + (long long)gm * ldc + gn] = f2bf(v);
                } else if constexpr (EPI == EPI_MLP) {
                    const long long idx = (long long)gm * ldc + gn;
                    v += bias[gn];
                    v = fmaxf(v, 0.0f);
                    float xv = bf2f(xb[idx]) + bf2f(ctxb[idx]) + v;  // x + ctx + relu
                    xb[idx] = f2bf(xv);
                } else {  // EPI_OUT
                    v += bias[gn];
                    ((float*)Cv)[(long long)gm * ldc + gn] = v;
                }
            }
        }
    }
}

// ---------------------------------------------------------------------------
// Setup mega-kernel: weight transposes (f32->bf16) + bias packing + embed.
// Grid (16,16, 4L+3), block (64,4).
//   z < 4L    : W transposes  (q,k,v,m)
//   z = 4L    : Wout transpose
//   z = 4L+1  : bqkv bias packing
//   z = 4L+2  : token embedding -> xb bf16 (256 blocks x 32 rows)
// ---------------------------------------------------------------------------
template <int L, int H, int V>
__global__ void setup_weights(const float* __restrict__ Wq, const float* __restrict__ Wk,
                              const float* __restrict__ Wv, const float* __restrict__ Wm,
                              const float* __restrict__ Wout,
                              const float* __restrict__ bq, const float* __restrict__ bk,
                              const float* __restrict__ bv,
                              u16* __restrict__ WqkvT, u16* __restrict__ WmT,
                              u16* __restrict__ WoutT, float* __restrict__ bqkv,
                              const int* __restrict__ tok, const float* __restrict__ emb,
                              u16* __restrict__ xbuf)
{
    const int z = blockIdx.z;
    if (z == 4 * L + 2) {
        const int blk = blockIdx.y * 16 + blockIdx.x;        // 0..255
        const int t   = threadIdx.y * 64 + threadIdx.x;      // 0..255
#pragma unroll 4
        for (int j = 0; j < 32; ++j) {
            const int row = blk * 32 + j;
            const int tk  = tok[row];
            float4 v = ((const float4*)(emb + (long long)tk * H))[t];
            uint2 p;
            p.x = (u32)f2bf(v.x) | ((u32)f2bf(v.y) << 16);
            p.y = (u32)f2bf(v.z) | ((u32)f2bf(v.w) << 16);
            ((uint2*)(xbuf + (long long)row * H))[t] = p;
        }
        return;
    }
    if (z == 4 * L + 1) {
        int i = ((blockIdx.y * 16 + blockIdx.x) * 256) + threadIdx.y * 64 + threadIdx.x;
        if (i < L * 3 * H) {
            int l = i / (3 * H), j = i % (3 * H);
            float v = (j < H) ? bq[l * H + j]
                    : (j < 2 * H) ? bk[l * H + j - H]
                                  : bv[l * H + j - 2 * H];
            bqkv[i] = v;
        }
        return;
    }

    const float* in;
    u16* outp;
    int inStride, outStride;
    if (z == 4 * L) {
        if (blockIdx.x >= V / 64) return;
        in = Wout; inStride = V;
        outp = WoutT; outStride = H;
    } else {
        const int which = z / L, l = z % L;
        inStride = H; outStride = H;
        if (which == 3) { in = Wm + (long long)l * H * H; outp = WmT + (long long)l * H * H; }
        else {
            in   = (which == 0 ? Wq : which == 1 ? Wk : Wv) + (long long)l * H * H;
            outp = WqkvT + (long long)l * 3 * H * H + (long long)which * H * H;
        }
    }

    __shared__ float tile[64][65];
    const int r0 = blockIdx.y * 64, c0 = blockIdx.x * 64;
    const int x = threadIdx.x, y = threadIdx.y;
#pragma unroll
    for (int j = 0; j < 16; ++j) {
        int r = y + j * 4;
        tile[r][x] = in[(long long)(r0 + r) * inStride + c0 + x];
    }
    __syncthreads();
#pragma unroll
    for (int j = 0; j < 16; ++j) {
        int r = y + j * 4;
        outp[(long long)(c0 + r) * outStride + r0 + x] = f2bf(tile[x][r]);
    }
}

// ---------------------------------------------------------------------------
// Causal column-softmax over k (batch = blockIdx.y), in-place probs (f32,
// exact zeros beyond the triangle) + attnT bf16 [q][k] emission.
// Grid (64, 8), block (16,64).
// ---------------------------------------------------------------------------
__global__ __launch_bounds__(1024) void attn_post(
    float* __restrict__ attn, long long aStride,
    u16* __restrict__ attnT, long long tStride)
{
    __shared__ float sm[64][16], sl[64][16], sm2[8][16], sl2[8][16];
    __shared__ float sM[16], sInv[16];

    const int b = blockIdx.y;
    float* base = attn + (long long)b * aStride;
    const int x = threadIdx.x, ky = threadIdx.y;
    const int q = blockIdx.x * 16 + x;

    float v[16];
    float m = -3.4e38f, l = 0.f;
#pragma unroll
    for (int j = 0; j < 16; ++j) {
        const int k = ky * 16 + j;
        float vj = NEG_INF_F;
        if (k <= q) vj = base[(long long)k * 1024 + q];
        v[j] = vj;
        float mn = fmaxf(m, vj);
        l = l * __expf(m - mn) + __expf(vj - mn);
        m = mn;
    }
    sm[ky][x] = m;
    sl[ky][x] = l;
    __syncthreads();
    if (ky < 8) {
        float M = -3.4e38f, L = 0.f;
#pragma unroll
        for (int t = 0; t < 8; ++t) {
            float mm = sm[ky + 8 * t][x], ll = sl[ky + 8 * t][x];
            float mn = fmaxf(M, mm);
            L = L * __expf(M - mn) + ll * __expf(mm - mn);
            M = mn;
        }
        sm2[ky][x] = M;
        sl2[ky][x] = L;
    }
    __syncthreads();
    if (ky == 0) {
        float M = -3.4e38f, L = 0.f;
#pragma unroll
        for (int t = 0; t < 8; ++t) {
            float mm = sm2[t][x], ll = sl2[t][x];
            float mn = fmaxf(M, mm);
            L = L * __expf(M - mn) + ll * __expf(mm - mn);
            M = mn;
        }
        sM[x]   = M;
        sInv[x] = 1.0f / L;
    }
    __syncthreads();
    const float M = sM[x], inv = sInv[x];

    u16 pb[16];
#pragma unroll
    for (int j = 0; j < 16; ++j) {
        float p = __expf(v[j] - M) * inv;   // masked: underflows to exact 0
        base[(long long)(ky * 16 + j) * 1024 + q] = p;
        pb[j] = f2bf(p);
    }
    u16* trow = attnT + (long long)b * tStride + (long long)q * 1024 + ky * 16;
    ((uint4*)trow)[0] = *(const uint4*)&pb[0];
    ((uint4*)trow)[1] = *(const uint4*)&pb[8];
}

// ---------------------------------------------------------------------------
extern "C" void kernel_launch(void* const* d_in, const int* in_sizes, int n_in,
                              void* d_out, int out_size, void* d_ws, size_t ws_size,
                              hipStream_t stream)
{
    const int*   tok  = (const int*)d_in[0];
    const float* emb  = (const float*)d_in[1];
    const float* Wq   = (const float*)d_in[2];
    const float* bq   = (const float*)d_in[3];
    const float* Wk   = (const float*)d_in[4];
    const float* bk   = (const float*)d_in[5];
    const float* Wv   = (const float*)d_in[6];
    const float* bv   = (const float*)d_in[7];
    const float* Wm   = (const float*)d_in[8];
    const float* bm   = (const float*)d_in[9];
    const float* Wout = (const float*)d_in[10];
    const float* bout = (const float*)d_in[11];
    float* out = (float*)d_out;

    constexpr int B = 8, S = 1024, H = 1024, V = 512, L = 6;
    constexpr long long M = (long long)B * S;  // 8192

    char* ws = (char*)d_ws;
    u16*   WqkvT = (u16*)ws;   ws += (long long)L * 3 * H * H * 2;  // [L][3H][H]
    u16*   WmT   = (u16*)ws;   ws += (long long)L * H * H * 2;      // [L][H][H]
    u16*   WoutT = (u16*)ws;   ws += (long long)V * H * 2;          // [V][H]
    float* bqkv  = (float*)ws; ws += (long long)L * 3 * H * 4;      // [L][3H]
    u16*   xb    = (u16*)ws;   ws += M * H * 2;                     // residual bf16
    u16*   QKV   = (u16*)ws;   ws += M * 2 * H * 2;                 // [M][2H] (q,k)
    u16*   attnT = (u16*)ws;   ws += (long long)B * S * S * 2;      // [b][q][k]
    u16*   Vt    = (u16*)ws;   ws += (long long)B * S * S * 2;      // [b][h][s]
    u16*   ctxb  = (u16*)ws;   ws += M * H * 2;                     // [M][H]

    float* attnOut = out + (long long)B * S * V;  // [L][B][S(key)][S(query)]

    setup_weights<L, H, V><<<dim3(16, 16, 4 * L + 3), dim3(64, 4), 0, stream>>>(
        Wq, Wk, Wv, Wm, Wout, bq, bk, bv, WqkvT, WmT, WoutT, bqkv, tok, emb, xb);

    for (int l = 0; l < L; ++l) {
        // merged: QK = xb @ [Wq|Wk] + bias -> QKV[M][2H]
        //         Vt = WvT @ xb^T + bv    -> Vt[b][h][s]   (1536 uniform blocks)
        gemm_bt<EPI_QKV><<<1536, 256, 0, stream>>>(
            xb, H, 0, WqkvT + (long long)l * 3 * H * H, H, 0,
            QKV, 2 * H, 0, H, bqkv + (long long)l * 3 * H, nullptr, Vt, 0.f, 0, 0);

        // logits[k,q] = K . Q * scale + mask  (lower-triangle tiles, batch/XCD)
        float* attnL = attnOut + (long long)l * B * S * S;
        gemm_bt<EPI_LOGITS><<<288, 256, 0, stream>>>(
            QKV + H, 2 * H, (long long)S * 2 * H,
            QKV, 2 * H, (long long)S * 2 * H,
            attnL, S, (long long)S * S, H,
            nullptr, nullptr, nullptr, 0.03125f, 0, 0);

        // softmax + attnT emission
        attn_post<<<dim3(64, 8), dim3(16, 64), 0, stream>>>(
            attnL, (long long)S * S, attnT, (long long)S * S);

        // ctx[q,h] = sum_{k<=q} attnT[q,k] * Vt[h,k]  (heavy-first q order)
        gemm_bt<EPI_CTX><<<512, 256, 0, stream>>>(
            attnT, S, (long long)S * S, Vt, S, (long long)S * S,
            ctxb, H, (long long)S * H, S,
            nullptr, nullptr, nullptr, 0.f, 0, 0);

        // xb = bf16( xb + ctx + relu(ctx @ Wm + bm) )
        gemm_bt<EPI_MLP><<<512, 256, 0, stream>>>(
            ctxb, H, 0, WmT + (long long)l * H * H, H, 0,
            nullptr, H, 0, H, bm + (long long)l * H, ctxb, xb, 0.f, 8, 64);
    }

    // out = xb @ Wout + bout  -> f32
    gemm_bt<EPI_OUT><<<256, 256, 0, stream>>>(
        xb, H, 0, WoutT, H, 0, out, V, 0, H,
        bout, nullptr, nullptr, 0.f, 4, 64);
}

// Round 5
// 1335.514 us; speedup vs baseline: 1.0491x; 1.0491x over previous
//
#include <hip/hip_runtime.h>
#include <stdint.h>

typedef unsigned short u16;
typedef unsigned int u32;
typedef __bf16 bf16x8 __attribute__((ext_vector_type(8)));
typedef float floatx4 __attribute__((ext_vector_type(4)));

#define NEG_INF_F (-10000000.0f)
#define MFMA16 __builtin_amdgcn_mfma_f32_16x16x32_bf16

__device__ __forceinline__ float bf2f(u16 u) {
    union { u32 u; float f; } x; x.u = ((u32)u) << 16; return x.f;
}
__device__ __forceinline__ u16 f2bf(float f) {
    union { float f; u32 u; } x; x.f = f;
    u32 r = x.u + 0x7fffu + ((x.u >> 16) & 1u);   // RNE
    return (u16)(r >> 16);
}

__device__ __forceinline__ void async_cp16(const void* g, void* l) {
    __builtin_amdgcn_global_load_lds(
        (const __attribute__((address_space(1))) void*)g,
        (__attribute__((address_space(3))) void*)l, 16, 0, 0);
}

// ---------------------------------------------------------------------------
// BT GEMM: C[m,n] = sum_k A[m,k] * B[n,k]
// 128x128 tile, 256 threads (4 waves 2x2), mfma_f32_16x16x32_bf16, BK=64,
// global_load_lds width-16 staging + 16B-group XOR swizzle (conflict-free).
// All grids are 1D with XCD-aware decode (block i -> XCD i&7 assumed).
// EPI_LOGITS: blocks 0..287 triangular k<=q tiles; blocks 288..2335 are
//   light V->Vt transpose blocks (dep: QKV only, same as logits) that fill
//   the 224 CUs idle during the 32-block second logits round -> transpose
//   is ~free and attn_post halves.
// EPI_CTX: q-tiles decoded heavy-first (byE = 7 - t>>3): LPT pairing gives
//   per-CU work 9 units (5+4,6+3,7+2,8+1) vs ascending's 12 (4+8).
// ---------------------------------------------------------------------------
enum { EPI_QKV = 0, EPI_LOGITS = 1, EPI_CTX = 2, EPI_MLP = 3, EPI_OUT = 4 };

template <int EPI>
__global__ __launch_bounds__(256) void gemm_bt(
    const u16* __restrict__ A, int lda, long long aBatch,
    const u16* __restrict__ B, int ldb, long long bBatch,
    void* __restrict__ Cv, int ldc, long long cBatch,
    int K,
    const float* __restrict__ bias,
    const u16* __restrict__ ctxb,      // EPI_MLP: ctx (read); EPI_LOGITS: QKV (V read)
    u16* __restrict__ xb,              // EPI_MLP: residual (rw); EPI_LOGITS: Vt (write)
    float scale, int nx, int ny)
{
    // sA padded +128 u16 so its u32 view holds a 64x65 transpose tile (16640 B).
    __shared__ __align__(16) u16 sA[128 * 64 + 128];
    __shared__ __align__(16) u16 sB[128 * 64];

    const int tid  = threadIdx.x;
    const int wave = tid >> 6;
    const int lane = tid & 63;

    int bxE, byE, bz;
    if constexpr (EPI == EPI_LOGITS) {
        if (blockIdx.x >= 288) {
            // ---- V -> Vt transpose zone (batch = (blk-288)&7 = blk&7 = XCD) ----
            const int t    = blockIdx.x - 288;
            const int b    = t & 7;
            const int tile = t >> 3;                        // 0..255
            const int s0 = (tile >> 4) * 64, h0 = (tile & 15) * 64;
            const u16* Vb = ctxb + (long long)b * (1024LL * 3072) + 2 * 1024;
            u16* Ob       = xb   + (long long)b * (1024LL * 1024);
            u32* tl = (u32*)sA;                             // [64][65] u32 view
            const int lr = tid >> 4, lc = tid & 15;
#pragma unroll
            for (int p = 0; p < 4; ++p) {
                const int s = p * 16 + lr;
                uint2 v = *(const uint2*)&Vb[(long long)(s0 + s) * 3072 + h0 + lc * 4];
                tl[s * 65 + lc * 4 + 0] = v.x & 0xffffu;
                tl[s * 65 + lc * 4 + 1] = v.x >> 16;
                tl[s * 65 + lc * 4 + 2] = v.y & 0xffffu;
                tl[s * 65 + lc * 4 + 3] = v.y >> 16;
            }
            __syncthreads();
#pragma unroll
            for (int p = 0; p < 4; ++p) {
                const int h = p * 16 + lr;
                uint2 o;
                o.x = tl[(lc * 4 + 0) * 65 + h] | (tl[(lc * 4 + 1) * 65 + h] << 16);
                o.y = tl[(lc * 4 + 2) * 65 + h] | (tl[(lc * 4 + 3) * 65 + h] << 16);
                *(uint2*)&Ob[(long long)(h0 + h) * 1024 + s0 + lc * 4] = o;
            }
            return;
        }
        bz = blockIdx.x & 7;
        int t = blockIdx.x >> 3;                       // 0..35 triangular
        int tq = (int)((sqrtf(8.0f * t + 1.0f) - 1.0f) * 0.5f);
        while ((tq + 1) * (tq + 2) / 2 <= t) ++tq;
        while (tq * (tq + 1) / 2 > t) --tq;
        bxE = tq;                       // n-tile = query
        byE = t - tq * (tq + 1) / 2;    // m-tile = key (<= tq)
    } else if constexpr (EPI == EPI_CTX) {
        bz = blockIdx.x & 7;
        int t = blockIdx.x >> 3;        // 0..63
        bxE = t & 7;                    // h-tile
        byE = 7 - (t >> 3);             // q-tile, heavy-first (LPT balance)
    } else {
        bz = 0;
        const int k = blockIdx.x & 7, r = blockIdx.x >> 3;
        if (nx >= 8) { const int xp = nx >> 3; bxE = xp * k + (r % xp); byE = r / xp; }
        else         { bxE = k >> 1; byE = (k & 1) * (ny >> 1) + r; }
    }
    int Keff = K;
    if constexpr (EPI == EPI_CTX) Keff = min(K, (byE + 1) * 128);

    const u16* Ab = A + (long long)bz * aBatch + (long long)(byE * 128) * lda;
    const u16* Bb = B + (long long)bz * bBatch + (long long)(bxE * 128) * ldb;

    const int wm = wave >> 1, wn = wave & 1;
    const int quad = lane >> 4;

    // staging: 16 calls/matrix, call c covers rows c*8..c*8+7 (8 lanes/row).
    const int srowoff = lane >> 3;
    const int gf      = (lane & 7) ^ ((lane >> 3) & 7);

    const int ra = 64 * wm + (lane & 15);
    const int rb = 64 * wn + (lane & 15);
    const int rx7 = lane & 7;

    floatx4 zero = {0.f, 0.f, 0.f, 0.f};
    floatx4 acc[4][4];
#pragma unroll
    for (int i = 0; i < 4; ++i)
#pragma unroll
        for (int j = 0; j < 4; ++j) acc[i][j] = zero;

    for (int k0 = 0; k0 < Keff; k0 += 64) {
#pragma unroll
        for (int i = 0; i < 4; ++i) {
            const int c = wave * 4 + i;
            const int r = c * 8 + srowoff;
            async_cp16(Ab + (long long)r * lda + k0 + gf * 8, &sA[c * 512 + lane * 8]);
            async_cp16(Bb + (long long)r * ldb + k0 + gf * 8, &sB[c * 512 + lane * 8]);
        }
        __syncthreads();

#pragma unroll
        for (int kk = 0; kk < 64; kk += 32) {
            const int gbase = kk >> 3;
            const int ga = ((gbase + quad) ^ rx7) << 3;
            bf16x8 af[4], bf[4];
#pragma unroll
            for (int mi = 0; mi < 4; ++mi)
                af[mi] = *(const bf16x8*)&sA[(ra + 16 * mi) * 64 + ga];
#pragma unroll
            for (int ni = 0; ni < 4; ++ni)
                bf[ni] = *(const bf16x8*)&sB[(rb + 16 * ni) * 64 + ga];
#pragma unroll
            for (int mi = 0; mi < 4; ++mi)
#pragma unroll
                for (int ni = 0; ni < 4; ++ni)
                    acc[mi][ni] = MFMA16(af[mi], bf[ni], acc[mi][ni], 0, 0, 0);
        }
        __syncthreads();
    }

    // epilogue: C/D layout col = lane&15, row = (lane>>4)*4 + reg  [m89-verified]
    const int m0 = byE * 128 + 64 * wm + (quad << 2);
    const int n0 = bxE * 128 + 64 * wn + (lane & 15);
#pragma unroll
    for (int mi = 0; mi < 4; ++mi) {
#pragma unroll
        for (int ni = 0; ni < 4; ++ni) {
            const int gn = n0 + ni * 16;
#pragma unroll
            for (int r = 0; r < 4; ++r) {
                const int gm = m0 + mi * 16 + r;
                float v = acc[mi][ni][r];
                if constexpr (EPI == EPI_QKV) {
                    v += bias[gn];
                    ((u16*)Cv)[(long long)gm * ldc + gn] = f2bf(v);
                } else if constexpr (EPI == EPI_LOGITS) {
                    v = v * scale + (gm > gn ? NEG_INF_F : 0.0f);  // m=key, n=query
                    ((float*)Cv)[(long long)bz * cBatch + (long long)gm * ldc + gn] = v;
                } else if constexpr (EPI == EPI_CTX) {
                    ((u16*)Cv)[(long long)bz * cBatch + (long long)gm * ldc + gn] = f2bf(v);
                } else if constexpr (EPI == EPI_MLP) {
                    const long long idx = (long long)gm * ldc + gn;
                    v += bias[gn];
                    v = fmaxf(v, 0.0f);
                    float xv = bf2f(xb[idx]) + bf2f(ctxb[idx]) + v;  // x + ctx + relu
                    xb[idx] = f2bf(xv);
                } else {  // EPI_OUT
                    v += bias[gn];
                    ((float*)Cv)[(long long)gm * ldc + gn] = v;
                }
            }
        }
    }
}

// ---------------------------------------------------------------------------
// Setup mega-kernel: weight transposes (f32->bf16) + bias packing.
// Grid (16,16, 4L+2), block (64,4).
// ---------------------------------------------------------------------------
template <int L, int H, int V>
__global__ void setup_weights(const float* __restrict__ Wq, const float* __restrict__ Wk,
                              const float* __restrict__ Wv, const float* __restrict__ Wm,
                              const float* __restrict__ Wout,
                              const float* __restrict__ bq, const float* __restrict__ bk,
                              const float* __restrict__ bv,
                              u16* __restrict__ WqkvT, u16* __restrict__ WmT,
                              u16* __restrict__ WoutT, float* __restrict__ bqkv)
{
    const int z = blockIdx.z;
    if (z == 4 * L + 1) {
        int i = ((blockIdx.y * 16 + blockIdx.x) * 256) + threadIdx.y * 64 + threadIdx.x;
        if (i < L * 3 * H) {
            int l = i / (3 * H), j = i % (3 * H);
            float v = (j < H) ? bq[l * H + j]
                    : (j < 2 * H) ? bk[l * H + j - H]
                                  : bv[l * H + j - 2 * H];
            bqkv[i] = v;
        }
        return;
    }

    const float* in;
    u16* outp;
    int inStride, outStride;
    if (z == 4 * L) {
        if (blockIdx.x >= V / 64) return;
        in = Wout; inStride = V;
        outp = WoutT; outStride = H;
    } else {
        const int which = z / L, l = z % L;
        inStride = H; outStride = H;
        if (which == 3) { in = Wm + (long long)l * H * H; outp = WmT + (long long)l * H * H; }
        else {
            in   = (which == 0 ? Wq : which == 1 ? Wk : Wv) + (long long)l * H * H;
            outp = WqkvT + (long long)l * 3 * H * H + (long long)which * H * H;
        }
    }

    __shared__ float tile[64][65];
    const int r0 = blockIdx.y * 64, c0 = blockIdx.x * 64;
    const int x = threadIdx.x, y = threadIdx.y;
#pragma unroll
    for (int j = 0; j < 16; ++j) {
        int r = y + j * 4;
        tile[r][x] = in[(long long)(r0 + r) * inStride + c0 + x];
    }
    __syncthreads();
#pragma unroll
    for (int j = 0; j < 16; ++j) {
        int r = y + j * 4;
        outp[(long long)(c0 + r) * outStride + r0 + x] = f2bf(tile[x][r]);
    }
}

// ---------------------------------------------------------------------------
// Causal column-softmax over k (batch = blockIdx.y), in-place probs (f32,
// exact zeros beyond the triangle) + attnT bf16 [q][k] emission.
// Grid (64, 8), block (16,64).
// ---------------------------------------------------------------------------
__global__ __launch_bounds__(1024) void attn_post(
    float* __restrict__ attn, long long aStride,
    u16* __restrict__ attnT, long long tStride)
{
    __shared__ float sm[64][16], sl[64][16], sm2[8][16], sl2[8][16];
    __shared__ float sM[16], sInv[16];

    const int b = blockIdx.y;
    float* base = attn + (long long)b * aStride;
    const int x = threadIdx.x, ky = threadIdx.y;
    const int q = blockIdx.x * 16 + x;

    float v[16];
    float m = -3.4e38f, l = 0.f;
#pragma unroll
    for (int j = 0; j < 16; ++j) {
        const int k = ky * 16 + j;
        float vj = NEG_INF_F;
        if (k <= q) vj = base[(long long)k * 1024 + q];
        v[j] = vj;
        float mn = fmaxf(m, vj);
        l = l * __expf(m - mn) + __expf(vj - mn);
        m = mn;
    }
    sm[ky][x] = m;
    sl[ky][x] = l;
    __syncthreads();
    if (ky < 8) {
        float M = -3.4e38f, L = 0.f;
#pragma unroll
        for (int t = 0; t < 8; ++t) {
            float mm = sm[ky + 8 * t][x], ll = sl[ky + 8 * t][x];
            float mn = fmaxf(M, mm);
            L = L * __expf(M - mn) + ll * __expf(mm - mn);
            M = mn;
        }
        sm2[ky][x] = M;
        sl2[ky][x] = L;
    }
    __syncthreads();
    if (ky == 0) {
        float M = -3.4e38f, L = 0.f;
#pragma unroll
        for (int t = 0; t < 8; ++t) {
            float mm = sm2[t][x], ll = sl2[t][x];
            float mn = fmaxf(M, mm);
            L = L * __expf(M - mn) + ll * __expf(mm - mn);
            M = mn;
        }
        sM[x]   = M;
        sInv[x] = 1.0f / L;
    }
    __syncthreads();
    const float M = sM[x], inv = sInv[x];

    u16 pb[16];
#pragma unroll
    for (int j = 0; j < 16; ++j) {
        float p = __expf(v[j] - M) * inv;   // masked: underflows to exact 0
        base[(long long)(ky * 16 + j) * 1024 + q] = p;
        pb[j] = f2bf(p);
    }
    u16* trow = attnT + (long long)b * tStride + (long long)q * 1024 + ky * 16;
    ((uint4*)trow)[0] = *(const uint4*)&pb[0];
    ((uint4*)trow)[1] = *(const uint4*)&pb[8];
}

// ---------------------------------------------------------------------------
__global__ void embed_kernel(const int* __restrict__ tok, const float* __restrict__ emb,
                             u16* __restrict__ xb)
{
    const int row = blockIdx.x;
    const int t   = tok[row];
    float4 v = ((const float4*)(emb + (long long)t * 1024))[threadIdx.x];
    uint2 p;
    p.x = (u32)f2bf(v.x) | ((u32)f2bf(v.y) << 16);
    p.y = (u32)f2bf(v.z) | ((u32)f2bf(v.w) << 16);
    ((uint2*)(xb + (long long)row * 1024))[threadIdx.x] = p;
}

// ---------------------------------------------------------------------------
extern "C" void kernel_launch(void* const* d_in, const int* in_sizes, int n_in,
                              void* d_out, int out_size, void* d_ws, size_t ws_size,
                              hipStream_t stream)
{
    const int*   tok  = (const int*)d_in[0];
    const float* emb  = (const float*)d_in[1];
    const float* Wq   = (const float*)d_in[2];
    const float* bq   = (const float*)d_in[3];
    const float* Wk   = (const float*)d_in[4];
    const float* bk   = (const float*)d_in[5];
    const float* Wv   = (const float*)d_in[6];
    const float* bv   = (const float*)d_in[7];
    const float* Wm   = (const float*)d_in[8];
    const float* bm   = (const float*)d_in[9];
    const float* Wout = (const float*)d_in[10];
    const float* bout = (const float*)d_in[11];
    float* out = (float*)d_out;

    constexpr int B = 8, S = 1024, H = 1024, V = 512, L = 6;
    constexpr long long M = (long long)B * S;  // 8192

    char* ws = (char*)d_ws;
    u16*   WqkvT = (u16*)ws;   ws += (long long)L * 3 * H * H * 2;  // [L][3H][H]
    u16*   WmT   = (u16*)ws;   ws += (long long)L * H * H * 2;      // [L][H][H]
    u16*   WoutT = (u16*)ws;   ws += (long long)V * H * 2;          // [V][H]
    float* bqkv  = (float*)ws; ws += (long long)L * 3 * H * 4;      // [L][3H]
    u16*   xb    = (u16*)ws;   ws += M * H * 2;                     // residual bf16
    u16*   QKV   = (u16*)ws;   ws += M * 3 * H * 2;                 // [M][3H]
    u16*   attnT = (u16*)ws;   ws += (long long)B * S * S * 2;      // [b][q][k]
    u16*   Vt    = (u16*)ws;   ws += (long long)B * S * S * 2;      // [b][h][s]
    u16*   ctxb  = (u16*)ws;   ws += M * H * 2;                     // [M][H]

    float* attnOut = out + (long long)B * S * V;  // [L][B][S(key)][S(query)]

    setup_weights<L, H, V><<<dim3(16, 16, 4 * L + 2), dim3(64, 4), 0, stream>>>(
        Wq, Wk, Wv, Wm, Wout, bq, bk, bv, WqkvT, WmT, WoutT, bqkv);
    embed_kernel<<<M, 256, 0, stream>>>(tok, emb, xb);

    for (int l = 0; l < L; ++l) {
        // QKV = xb @ [Wq|Wk|Wv] + bias  -> bf16 [M][3H]
        gemm_bt<EPI_QKV><<<1536, 256, 0, stream>>>(
            xb, H, 0, WqkvT + (long long)l * 3 * H * H, H, 0,
            QKV, 3 * H, 0, H, bqkv + l * 3 * H, nullptr, nullptr, 0.f, 24, 64);

        // logits[k,q] = K . Q * scale + mask  (288 triangular GEMM blocks)
        // + V->Vt transpose (2048 light blocks, hidden in the ragged tail)
        float* attnL = attnOut + (long long)l * B * S * S;
        gemm_bt<EPI_LOGITS><<<288 + 2048, 256, 0, stream>>>(
            QKV + H, 3 * H, (long long)S * 3 * H,
            QKV, 3 * H, (long long)S * 3 * H,
            attnL, S, (long long)S * S, H,
            nullptr, QKV, Vt, 0.03125f, 0, 0);

        // softmax + attnT emission (softmax-only now)
        attn_post<<<dim3(64, 8), dim3(16, 64), 0, stream>>>(
            attnL, (long long)S * S, attnT, (long long)S * S);

        // ctx[q,h] = sum_{k<=q} attnT[q,k] * Vt[h,k]  (heavy-first q order)
        gemm_bt<EPI_CTX><<<512, 256, 0, stream>>>(
            attnT, S, (long long)S * S, Vt, S, (long long)S * S,
            ctxb, H, (long long)S * H, S,
            nullptr, nullptr, nullptr, 0.f, 0, 0);

        // xb = bf16( xb + ctx + relu(ctx @ Wm + bm) )
        gemm_bt<EPI_MLP><<<512, 256, 0, stream>>>(
            ctxb, H, 0, WmT + (long long)l * H * H, H, 0,
            nullptr, H, 0, H, bm + l * H, ctxb, xb, 0.f, 8, 64);
    }

    // out = xb @ Wout + bout  -> f32
    gemm_bt<EPI_OUT><<<256, 256, 0, stream>>>(
        xb, H, 0, WoutT, H, 0, out, V, 0, H,
        bout, nullptr, nullptr, 0.f, 4, 64);
}